// Round 14
// baseline (251.568 us; speedup 1.0000x reference)
//
#include <hip/hip_runtime.h>

// ---- problem constants (fixed by reference setup_inputs) ----
constexpr int B_  = 32;
constexpr int Na  = 512;
constexpr int Nv  = 256;
constexpr int D   = 384;

constexpr int NK  = 12;        // 12 k-chunks of 32

// fp8 operand regions: one 32-row group x 384 k = 12 chunks x 1 KB = 12 KB.
// Chunk layout: byte = h2*512 + r*16 + j  -> value[row r][k = kc*32 + h2*16 + j].
// MFMA operand read at lane*16: free=(lane&31), k-half=(lane>>5); both MFMA
// k-halves (A.x/A.y with B.x/B.y) share one consistent k-permutation => exact.
constexpr int AGROUPS = B_ * 16;   // 512 groups (audio rows g*32..+31)
constexpr int BGROUPS = B_ * 8;    // 256 groups (visual rows g*32..+31)
constexpr size_t GROUP_BYTES = 12 * 1024;

typedef long  long2v   __attribute__((ext_vector_type(2)));
typedef int   int4v    __attribute__((ext_vector_type(4)));
typedef float floatx16 __attribute__((ext_vector_type(16)));

// 16B-per-lane async global->LDS (lane i writes LDS slot base + i*16)
__device__ __forceinline__ void async_load16(const void* g, void* l) {
    __builtin_amdgcn_global_load_lds(
        (const __attribute__((address_space(1))) unsigned int*)g,
        (__attribute__((address_space(3))) unsigned int*)l,
        16, 0, 0);
}

// ---- K1: zero output + fp32 -> fp8(e4m3 OCP), both sides coalesced ----
// ONE pass per block (grid = 768 groups x 3 passes): thread t -> row r=t>>3,
// q=t&7; reads 16 consecutive floats of row r at k0=p*128+q*16 (8 threads
// span a row's 512 B, coalesced), emits one 16 B slot; a wave's 64 stores
// form 16 full 64 B lines.
__global__ void convert_fp8_kernel(const float* __restrict__ a, const float* __restrict__ v,
                                   unsigned char* __restrict__ a8,
                                   unsigned char* __restrict__ b8,
                                   float* __restrict__ out) {
    int gid = blockIdx.x * blockDim.x + threadIdx.x;
    if (gid < B_ * B_) out[gid] = 0.0f;    // d_out is poisoned before every launch

    int blk   = blockIdx.x;
    int group = blk / 3;
    int p     = blk - group * 3;

    const float* src;
    unsigned char* dst;
    if (group < AGROUPS) {
        src = a + (size_t)group * 32 * D;
        dst = a8 + (size_t)group * GROUP_BYTES;
    } else {
        int g2 = group - AGROUPS;
        src = v + (size_t)g2 * 32 * D;
        dst = b8 + (size_t)g2 * GROUP_BYTES;
    }
    const int t = threadIdx.x;
    const int r = t >> 3, q = t & 7;

    int k0 = p * 128 + q * 16;
    const float4* s4 = (const float4*)(src + (size_t)r * D + k0);
    float4 f0 = s4[0], f1 = s4[1], f2 = s4[2], f3 = s4[3];
    int w0 = 0, w1 = 0, w2 = 0, w3 = 0;
    w0 = __builtin_amdgcn_cvt_pk_fp8_f32(f0.x, f0.y, w0, false);
    w0 = __builtin_amdgcn_cvt_pk_fp8_f32(f0.z, f0.w, w0, true);
    w1 = __builtin_amdgcn_cvt_pk_fp8_f32(f1.x, f1.y, w1, false);
    w1 = __builtin_amdgcn_cvt_pk_fp8_f32(f1.z, f1.w, w1, true);
    w2 = __builtin_amdgcn_cvt_pk_fp8_f32(f2.x, f2.y, w2, false);
    w2 = __builtin_amdgcn_cvt_pk_fp8_f32(f2.z, f2.w, w2, true);
    w3 = __builtin_amdgcn_cvt_pk_fp8_f32(f3.x, f3.y, w3, false);
    w3 = __builtin_amdgcn_cvt_pk_fp8_f32(f3.z, f3.w, w3, true);
    int kc = k0 >> 5;
    int h2 = (k0 >> 4) & 1;
    int4v o = { w0, w1, w2, w3 };
    *(int4v*)(dst + (size_t)kc * 1024 + h2 * 512 + r * 16) = o;
}

// ---- K2: fused fp8 GEMM (32x32x16 fp8_fp8) + logsumexp-pool, BARRIERLESS k-loop ----
// Block = (bi, bj, nh): 256 audio rows (4 chunks of 64) x full 256 cols, done
// as 2 sequential col-half phases. Per phase: stage the 48 KB B half-panel
// into LDS ONCE (12 async_load16 per wave), barrier, then the entire
// 4-nc x 12-k MFMA loop runs with NO barriers (B read-only resident; A goes
// global->regs per wave, distance-1 prefetch). 3 barriers per block total —
// the per-iter vmcnt(0) drain that capped rounds 5-13 is gone.
// Col-half partial sums are additive (linear sums, not LSE), accumulated in
// ms[4][64][2] by the SAME wave in both phases (no race).
// acc = 2 x floatx16 = 32 AGPRs; LDS 50 KB -> 3 blocks/CU = 12 waves/CU.
__global__ __launch_bounds__(256, 3) void gemm_lse_kernel(
        const unsigned char* __restrict__ a8,
        const unsigned char* __restrict__ b8,
        float* __restrict__ out)
{
    __shared__ unsigned char blds[NK * 4 * 1024];  // 48 KB: [kc][ctl (4 col-tiles)]
    __shared__ float ms[4][64][2];                 // [ncl][row][col-quarter-pair]
    __shared__ float wsum[4];

    // hierarchical decode: consecutive bids share bj-panels / bi-rows in L2
    int t = blockIdx.x;
    const int nh    = t & 1;          t >>= 1;
    const int bj_lo = t & 15;         t >>= 4;
    const int bi_lo = t & 7;          t >>= 3;
    const int bj_hi = t & 1;          t >>= 1;
    const int bi    = t * 8 + bi_lo;
    const int bj    = bj_hi * 16 + bj_lo;

    const int tid  = threadIdx.x;
    const int lane = tid & 63;
    const int wave = tid >> 6;
    const int rt   = wave >> 1;    // row tile (32 rows) within a 64-row chunk
    const int cw   = wave & 1;     // 64-col half within the phase's 128 cols

    const size_t laneoff = (size_t)lane * 16;
    const unsigned char* bpanel = b8 + (size_t)(bj * 8) * GROUP_BYTES;

    constexpr float INV_TAU_LN2 = 0.7213475204444817f;  // 1/(tau*ln2), tau=2
    constexpr float TAU_LN2     = 1.3862943611198906f;  // tau*ln2

    for (int ch = 0; ch < 2; ++ch) {
        if (ch) __syncthreads();   // all reads of the previous B half done

        // stage B half-panel: wave stages col-tile group (ch*4 + wave), 12 KB
        {
            const unsigned char* src = bpanel + (size_t)(ch * 4 + wave) * GROUP_BYTES;
            #pragma unroll
            for (int kc = 0; kc < NK; ++kc)
                async_load16(src + (size_t)kc * 1024 + laneoff,
                             (void*)&blds[(kc * 4 + wave) * 1024]);
        }
        __syncthreads();           // drain staging; B now resident + read-only

        for (int ncl = 0; ncl < 4; ++ncl) {
            const int rg = (nh * 4 + ncl) * 2 + rt;
            const unsigned char* abase = a8 + (size_t)(bi * 16 + rg) * GROUP_BYTES;

            long2v A = *(const long2v*)(abase + laneoff), nA;
            floatx16 acc[2];
            acc[0] = (floatx16)(0.0f);
            acc[1] = (floatx16)(0.0f);

            #pragma unroll
            for (int k = 0; k < NK; ++k) {
                nA = A;
                if (k + 1 < NK)
                    nA = *(const long2v*)(abase + (size_t)(k + 1) * 1024 + laneoff);

                const unsigned char* bk = &blds[k * 4096 + cw * 2048];
                long2v B0 = *(const long2v*)(bk + lane * 16);
                long2v B1 = *(const long2v*)(bk + 1024 + lane * 16);
                acc[0] = __builtin_amdgcn_mfma_f32_32x32x16_fp8_fp8(A.x, B0.x, acc[0], 0, 0, 0);
                acc[1] = __builtin_amdgcn_mfma_f32_32x32x16_fp8_fp8(A.x, B1.x, acc[1], 0, 0, 0);
                acc[0] = __builtin_amdgcn_mfma_f32_32x32x16_fp8_fp8(A.y, B0.y, acc[0], 0, 0, 0);
                acc[1] = __builtin_amdgcn_mfma_f32_32x32x16_fp8_fp8(A.y, B1.y, acc[1], 0, 0, 0);
                A = nA;
            }

            // per-row sum of exp2 over this wave's 64 cols (no max: |sims/tau|
            // <= ~55 so exp2 within fp32 range; exact).
            // C/D (shape-determined): col = lane&31, row = (reg&3)+8*(reg>>2)+4*(lane>>5)
            #pragma unroll
            for (int reg = 0; reg < 16; ++reg) {
                float s = exp2f(acc[0][reg] * INV_TAU_LN2)
                        + exp2f(acc[1][reg] * INV_TAU_LN2);
                #pragma unroll
                for (int m = 1; m < 32; m <<= 1)
                    s += __shfl_xor(s, m, 64);
                if ((lane & 31) == 0) {
                    int row = rt * 32 + (reg & 3) + 8 * (reg >> 2) + 4 * (lane >> 5);
                    if (ch == 0) ms[ncl][row][cw]  = s;   // phase 0: write
                    else         ms[ncl][row][cw] += s;   // phase 1: same-wave accumulate
                }
            }
        }
    }
    __syncthreads();

    // final: one row per thread (4 ncl x 64 rows = 256), lse + block reduction
    {
        const int ncl = tid >> 6, row = tid & 63;
        float s = ms[ncl][row][0] + ms[ncl][row][1];
        float lse = TAU_LN2 * log2f(s);
        #pragma unroll
        for (int d = 1; d < 64; d <<= 1) lse += __shfl_xor(lse, d, 64);
        if (lane == 0) wsum[wave] = lse;
    }
    __syncthreads();
    if (tid == 0)
        atomicAdd(&out[bi * 32 + bj],
                  (wsum[0] + wsum[1] + wsum[2] + wsum[3]) * (1.0f / Na));
}

extern "C" void kernel_launch(void* const* d_in, const int* in_sizes, int n_in,
                              void* d_out, int out_size, void* d_ws, size_t ws_size,
                              hipStream_t stream) {
    const float* audio  = (const float*)d_in[0];
    const float* visual = (const float*)d_in[1];
    float* out = (float*)d_out;

    unsigned char* a8 = (unsigned char*)d_ws;                        // 6.29 MB fp8 A
    unsigned char* b8 = a8 + (size_t)AGROUPS * GROUP_BYTES;          // +3.15 MB fp8 B

    convert_fp8_kernel<<<dim3((AGROUPS + BGROUPS) * 3), dim3(256), 0, stream>>>(
        audio, visual, a8, b8, out);
    // grid: 32 bi x 32 bj x 2 nh = 2048 blocks, each 256 rows x full 256 cols
    gemm_lse_kernel<<<dim3(B_ * B_ * 2), dim3(256), 0, stream>>>(a8, b8, out);
}

// Round 15
// 174.503 us; speedup vs baseline: 1.4416x; 1.4416x over previous
//
#include <hip/hip_runtime.h>

// ---- problem constants (fixed by reference setup_inputs) ----
constexpr int B_  = 32;
constexpr int Na  = 512;
constexpr int Nv  = 256;
constexpr int D   = 384;

constexpr int NK  = 12;        // 12 k-chunks of 32

// fp8 operand regions: one 32-row group x 384 k = 12 chunks x 1 KB = 12 KB.
// Chunk layout: byte = h2*512 + r*16 + j  -> value[row r][k = kc*32 + h2*16 + j].
// Lane l reads 16 B at l*16: rows l&31, k-slots {(l>>5)*16 .. +16}. The MFMA
// pairing (A.x,B.x) then (A.y,B.y) applies the SAME k-slot permutation to A
// and B, so each 32-k chunk is covered exactly once => exact dot product.
constexpr int AGROUPS = B_ * 16;   // 512 groups (audio rows g*32..+31)
constexpr int BGROUPS = B_ * 8;    // 256 groups (visual rows g*32..+31)
constexpr size_t GROUP_BYTES = 12 * 1024;

typedef long  long2v   __attribute__((ext_vector_type(2)));
typedef int   int4v    __attribute__((ext_vector_type(4)));
typedef float floatx16 __attribute__((ext_vector_type(16)));

// 16B-per-lane async global->LDS (lane i writes LDS slot base + i*16)
__device__ __forceinline__ void async_load16(const void* g, void* l) {
    __builtin_amdgcn_global_load_lds(
        (const __attribute__((address_space(1))) unsigned int*)g,
        (__attribute__((address_space(3))) unsigned int*)l,
        16, 0, 0);
}

// ---- K1: zero output + fp32 -> fp8(e4m3 OCP), both sides coalesced ----
__global__ void convert_fp8_kernel(const float* __restrict__ a, const float* __restrict__ v,
                                   unsigned char* __restrict__ a8,
                                   unsigned char* __restrict__ b8,
                                   float* __restrict__ out) {
    int gid = blockIdx.x * blockDim.x + threadIdx.x;
    if (gid < B_ * B_) out[gid] = 0.0f;    // d_out is poisoned before every launch

    int blk   = blockIdx.x;
    int group = blk / 3;
    int p     = blk - group * 3;

    const float* src;
    unsigned char* dst;
    if (group < AGROUPS) {
        src = a + (size_t)group * 32 * D;
        dst = a8 + (size_t)group * GROUP_BYTES;
    } else {
        int g2 = group - AGROUPS;
        src = v + (size_t)g2 * 32 * D;
        dst = b8 + (size_t)g2 * GROUP_BYTES;
    }
    const int t = threadIdx.x;
    const int r = t >> 3, q = t & 7;

    int k0 = p * 128 + q * 16;
    const float4* s4 = (const float4*)(src + (size_t)r * D + k0);
    float4 f0 = s4[0], f1 = s4[1], f2 = s4[2], f3 = s4[3];
    int w0 = 0, w1 = 0, w2 = 0, w3 = 0;
    w0 = __builtin_amdgcn_cvt_pk_fp8_f32(f0.x, f0.y, w0, false);
    w0 = __builtin_amdgcn_cvt_pk_fp8_f32(f0.z, f0.w, w0, true);
    w1 = __builtin_amdgcn_cvt_pk_fp8_f32(f1.x, f1.y, w1, false);
    w1 = __builtin_amdgcn_cvt_pk_fp8_f32(f1.z, f1.w, w1, true);
    w2 = __builtin_amdgcn_cvt_pk_fp8_f32(f2.x, f2.y, w2, false);
    w2 = __builtin_amdgcn_cvt_pk_fp8_f32(f2.z, f2.w, w2, true);
    w3 = __builtin_amdgcn_cvt_pk_fp8_f32(f3.x, f3.y, w3, false);
    w3 = __builtin_amdgcn_cvt_pk_fp8_f32(f3.z, f3.w, w3, true);
    int kc = k0 >> 5;
    int h2 = (k0 >> 4) & 1;
    int4v o = { w0, w1, w2, w3 };
    *(int4v*)(dst + (size_t)kc * 1024 + h2 * 512 + r * 16) = o;
}

// ---- K2: fused fp8 GEMM (32x32x16 fp8_fp8) + logsumexp-pool ----
// A ENTIRELY IN REGISTERS: each wave owns one 32-row group; its full 384-k
// panel = 12 KB = 48 VGPRs, loaded once (12 coalesced 1 KB bursts) and kept
// across BOTH col-half phases. Per phase: stage 48 KB B half-panel to LDS,
// barrier, then 12 x (4 ds_read_b128 + 8 MFMA) with ZERO global loads and
// ZERO barriers in the k-loop. 4 barriers per block total.
// Round-14 lesson: 4 MFMAs of latency cover per in-loop A-load is a stall
// machine; round-13 lesson: per-iter vmcnt(0) barrier drain caps at 40%.
// This structure has neither. acc 64 + A 48 + ~40 misc ~= 152 regs <= 170
// (__launch_bounds__(256,3)); LDS 48.6 KB -> 3 blocks/CU = 12 waves.
__global__ __launch_bounds__(256, 3) void gemm_lse_kernel(
        const unsigned char* __restrict__ a8,
        const unsigned char* __restrict__ b8,
        float* __restrict__ out)
{
    __shared__ unsigned char blds[NK * 4 * 1024];  // 48 KB: [kc][4 col-tiles]
    __shared__ float ms[4][32];                    // [wave][row] phase-accumulated
    __shared__ float wsum[2];

    // decode: 512-bid window = 8 bi x 16 bj x 4 nh (A 1.5 MB + B 1.5 MB in L2)
    int t = blockIdx.x;
    const int nh    = t & 3;          t >>= 2;
    const int bj_lo = t & 15;         t >>= 4;
    const int bi_lo = t & 7;          t >>= 3;
    const int bj_hi = t & 1;          t >>= 1;
    const int bi    = t * 8 + bi_lo;
    const int bj    = bj_hi * 16 + bj_lo;

    const int tid  = threadIdx.x;
    const int lane = tid & 63;
    const int wave = tid >> 6;

    const size_t laneoff = (size_t)lane * 16;
    const unsigned char* bpanel = b8 + (size_t)(bj * 8) * GROUP_BYTES;
    const unsigned char* abase  = a8 + (size_t)(bi * 16 + nh * 4 + wave) * GROUP_BYTES;

    constexpr float INV_TAU_LN2 = 0.7213475204444817f;  // 1/(tau*ln2), tau=2
    constexpr float TAU_LN2     = 1.3862943611198906f;  // tau*ln2

    long2v A[NK];   // 48 VGPRs: this wave's complete A panel

    for (int ch = 0; ch < 2; ++ch) {
        if (ch) __syncthreads();       // all waves done reading previous B half

        // stage B half-panel: wave stages col-tile group (ch*4 + wave), 12 KB
        {
            const unsigned char* src = bpanel + (size_t)(ch * 4 + wave) * GROUP_BYTES;
            #pragma unroll
            for (int kc = 0; kc < NK; ++kc)
                async_load16(src + (size_t)kc * 1024 + laneoff,
                             (void*)&blds[(kc * 4 + wave) * 1024]);
        }
        if (ch == 0) {                 // burst-load A panel (overlaps B staging)
            #pragma unroll
            for (int kc = 0; kc < NK; ++kc)
                A[kc] = *(const long2v*)(abase + (size_t)kc * 1024 + laneoff);
        }
        __syncthreads();               // drain staging (and A loads, first pass)

        floatx16 acc[4];
        #pragma unroll
        for (int ct = 0; ct < 4; ++ct) acc[ct] = (floatx16)(0.0f);

        #pragma unroll
        for (int k = 0; k < NK; ++k) {
            const unsigned char* bk = &blds[k * 4096];
            long2v Bv[4];
            #pragma unroll
            for (int ct = 0; ct < 4; ++ct)
                Bv[ct] = *(const long2v*)(bk + ct * 1024 + lane * 16);
            #pragma unroll
            for (int ct = 0; ct < 4; ++ct)
                acc[ct] = __builtin_amdgcn_mfma_f32_32x32x16_fp8_fp8(A[k].x, Bv[ct].x, acc[ct], 0, 0, 0);
            #pragma unroll
            for (int ct = 0; ct < 4; ++ct)
                acc[ct] = __builtin_amdgcn_mfma_f32_32x32x16_fp8_fp8(A[k].y, Bv[ct].y, acc[ct], 0, 0, 0);
        }

        // per-row partial sums of exp2 over this phase's 128 cols (no max:
        // |sims/tau| <= ~55, exp2 within fp32 range; exact).
        // C/D (shape-determined): col = lane&31, row = (reg&3)+8*(reg>>2)+4*(lane>>5)
        #pragma unroll
        for (int reg = 0; reg < 16; ++reg) {
            float s = exp2f(acc[0][reg] * INV_TAU_LN2)
                    + exp2f(acc[1][reg] * INV_TAU_LN2)
                    + exp2f(acc[2][reg] * INV_TAU_LN2)
                    + exp2f(acc[3][reg] * INV_TAU_LN2);
            #pragma unroll
            for (int m = 1; m < 32; m <<= 1)
                s += __shfl_xor(s, m, 64);
            if ((lane & 31) == 0) {
                int row = (reg & 3) + 8 * (reg >> 2) + 4 * (lane >> 5);
                if (ch == 0) ms[wave][row]  = s;   // same wave accumulates both
                else         ms[wave][row] += s;   // phases: no race
            }
        }
    }
    __syncthreads();

    // final: 128 rows; thread t<128 -> row (t>>5 wave-group, t&31 row), lse,
    // block-sum, one atomicAdd
    if (tid < 128) {
        float s = ms[tid >> 5][tid & 31];
        float lse = TAU_LN2 * log2f(s);
        #pragma unroll
        for (int d = 1; d < 64; d <<= 1) lse += __shfl_xor(lse, d, 64);
        if ((tid & 63) == 0) wsum[tid >> 6] = lse;
    }
    __syncthreads();
    if (tid == 0)
        atomicAdd(&out[bi * 32 + bj], (wsum[0] + wsum[1]) * (1.0f / Na));
}

extern "C" void kernel_launch(void* const* d_in, const int* in_sizes, int n_in,
                              void* d_out, int out_size, void* d_ws, size_t ws_size,
                              hipStream_t stream) {
    const float* audio  = (const float*)d_in[0];
    const float* visual = (const float*)d_in[1];
    float* out = (float*)d_out;

    unsigned char* a8 = (unsigned char*)d_ws;                        // 6.29 MB fp8 A
    unsigned char* b8 = a8 + (size_t)AGROUPS * GROUP_BYTES;          // +3.15 MB fp8 B

    convert_fp8_kernel<<<dim3((AGROUPS + BGROUPS) * 3), dim3(256), 0, stream>>>(
        audio, visual, a8, b8, out);
    // grid: 32 bi x 32 bj x 4 nh = 4096 blocks, each 128 rows x full 256 cols
    gemm_lse_kernel<<<dim3(B_ * B_ * 4), dim3(256), 0, stream>>>(a8, b8, out);
}